// Round 1
// 414.879 us; speedup vs baseline: 1.0234x; 1.0234x over previous
//
#include <hip/hip_runtime.h>
#include <math.h>

#define NH    24
#define DM    512
#define DP    128
#define EMAX  2048
#define DIN   3584   // 512 + 24*128
#define B     64
#define SLABS 16     // K slabs in mlp1
#define SROWS 224    // rows per slab (16*224 = 3584)

// ws layout (floats):
//   x_T   [DIN][B]       = 229376 f
//   part  [SLABS][B][DM] = 524288 f

// ---------------------------------------------------------------------------
// K1: per-(b,h) bin mean of episode_ctx (contiguous slice), project through
//     W_pool, write x_T[512 + h*128 + k][b]. Block h==24 copies day_embed.
// grid (25, 64), block 256
// Mean phase: float4 loads, thread t = (ep_parity = t>>7, dim-quad p = t&127);
// unroll 4 -> 4 episodes (8 KB) in flight per thread pair.
// ---------------------------------------------------------------------------
__global__ void binpool_kernel(const float* __restrict__ day_embed,
                               const float* __restrict__ episode_ctx,
                               const int* __restrict__ n_episodes,
                               const float* __restrict__ W_pool,
                               const float* __restrict__ b_pool,
                               float* __restrict__ x_T) {
    const int h = blockIdx.x;   // 0..24 (24 == day_embed copy)
    const int b = blockIdx.y;
    const int t = threadIdx.x;  // 0..255

    if (h == NH) {
        for (int i = t; i < DM; i += 256)
            x_T[(size_t)i * B + b] = day_embed[b * DM + i];
        return;
    }

    const int n  = n_episodes[b];
    int bs = n / NH; if (bs < 1) bs = 1;
    const int lo = h * bs;
    int hi = lo + bs; if (hi > n) hi = n;
    int count = hi - lo; if (count < 0) count = 0;

    __shared__ float4 sh4[256];
    __shared__ float  sh_mean[DM];

    const int p  = t & 127;     // dim quad: dims 4p..4p+3
    const int eo = t >> 7;      // episode parity

    float4 a = make_float4(0.f, 0.f, 0.f, 0.f);
    const float4* base = (const float4*)episode_ctx
                       + (size_t)b * EMAX * (DM / 4) + p;
    #pragma unroll 4
    for (int e = lo + eo; e < hi; e += 2) {
        float4 v = base[(size_t)e * (DM / 4)];
        a.x += v.x; a.y += v.y; a.z += v.z; a.w += v.w;
    }
    sh4[t] = a;
    __syncthreads();

    if (t < 128) {
        const float inv = (count > 0) ? (1.0f / (float)count) : 0.0f;
        float4 u = sh4[t], v = sh4[t + 128];
        sh_mean[4 * t]     = (u.x + v.x) * inv;
        sh_mean[4 * t + 1] = (u.y + v.y) * inv;
        sh_mean[4 * t + 2] = (u.z + v.z) * inv;
        sh_mean[4 * t + 3] = (u.w + v.w) * inv;
    }
    __syncthreads();

    // projection: thread t<64 computes outputs k = 2t, 2t+1
    if (t < 64) {
        float c0 = 0.f, c1 = 0.f;
        const float2* wp = (const float2*)W_pool + t;
        #pragma unroll 4
        for (int d = 0; d < DM; ++d) {
            float m = sh_mean[d];
            float2 w = wp[(size_t)d * (DP / 2)];
            c0 += m * w.x;
            c1 += m * w.y;
        }
        const int row = DM + h * DP + 2 * t;
        if (count > 0) {
            x_T[(size_t)row * B + b]       = c0 + b_pool[2 * t];
            x_T[(size_t)(row + 1) * B + b] = c1 + b_pool[2 * t + 1];
        } else {
            x_T[(size_t)row * B + b]       = 0.f;
            x_T[(size_t)(row + 1) * B + b] = 0.f;
        }
    }
}

// ---------------------------------------------------------------------------
// K2: partial GEMM  part[s] = X^T slab . W1 slab
// grid (32, 16): c = 16-col chunk, s = K slab (224 rows). block 256 = 4 waves
// -> 512 blocks = 2 blocks/CU (8 waves/CU) for latency hiding.
// wave w: k in [224s + 56w, +56). lane = batch row (coalesced x_T reads);
// W1 chunk is wave-uniform, float4 loads.
// ---------------------------------------------------------------------------
__global__ void mlp1_kernel(const float* __restrict__ x_T,
                            const float* __restrict__ W1,
                            float* __restrict__ part) {
    const int c = blockIdx.x;
    const int s = blockIdx.y;
    const int t = threadIdx.x;
    const int w = t >> 6;
    const int lane = t & 63;

    float acc[16];
    #pragma unroll
    for (int j = 0; j < 16; ++j) acc[j] = 0.f;

    const int k0 = SROWS * s + 56 * w;
    const float4* wbase = (const float4*)(W1 + (size_t)k0 * DM + 16 * c);
    const float* xbase = x_T + (size_t)k0 * B + lane;

    #pragma unroll 4
    for (int ki = 0; ki < 56; ++ki) {
        float xv = xbase[ki * B];
        const float4* wrow = wbase + (size_t)ki * (DM / 4);
        #pragma unroll
        for (int q = 0; q < 4; ++q) {
            float4 wv = wrow[q];
            acc[4 * q]     += xv * wv.x;
            acc[4 * q + 1] += xv * wv.y;
            acc[4 * q + 2] += xv * wv.z;
            acc[4 * q + 3] += xv * wv.w;
        }
    }

    __shared__ float red[4][64][17];
    #pragma unroll
    for (int j = 0; j < 16; ++j)
        red[w][lane][j] = acc[j];
    __syncthreads();

    for (int idx = t; idx < 1024; idx += 256) {
        const int row = idx >> 4;
        const int j   = idx & 15;
        float v = red[0][row][j] + red[1][row][j] + red[2][row][j] + red[3][row][j];
        part[(size_t)s * (B * DM) + (size_t)row * DM + 16 * c + j] = v;
    }
}

// ---------------------------------------------------------------------------
// K3: per-b: h = gelu(sum_s part[s][b] + b1); out[b] = h @ W2 + b2
// grid 64, block 256
// ---------------------------------------------------------------------------
__global__ void tail_kernel(const float* __restrict__ part,
                            const float* __restrict__ b1,
                            const float* __restrict__ W2,
                            const float* __restrict__ b2,
                            float* __restrict__ out) {
    const int b = blockIdx.x;
    const int t = threadIdx.x;

    __shared__ float sh_h[DM];

    #pragma unroll
    for (int rep = 0; rep < 2; ++rep) {
        const int col = t + rep * 256;
        float v0 = 0.f, v1 = 0.f;
        #pragma unroll
        for (int s = 0; s < SLABS; s += 2) {
            v0 += part[(size_t)s * (B * DM) + (size_t)b * DM + col];
            v1 += part[(size_t)(s + 1) * (B * DM) + (size_t)b * DM + col];
        }
        float v = v0 + v1 + b1[col];
        sh_h[col] = 0.5f * v * (1.0f + erff(v * 0.70710678118654752f));
    }
    __syncthreads();

    if (t < 64) {
        float a0 = 0.f, a1 = 0.f;
        #pragma unroll
        for (int i = t; i < DM; i += 64) {
            float hv = sh_h[i];
            float2 w = ((const float2*)W2)[i];
            a0 += hv * w.x;
            a1 += hv * w.y;
        }
        #pragma unroll
        for (int off = 32; off > 0; off >>= 1) {
            a0 += __shfl_down(a0, off);
            a1 += __shfl_down(a1, off);
        }
        if (t == 0) {
            out[b * 2]     = a0 + b2[0];
            out[b * 2 + 1] = a1 + b2[1];
        }
    }
}

extern "C" void kernel_launch(void* const* d_in, const int* in_sizes, int n_in,
                              void* d_out, int out_size, void* d_ws, size_t ws_size,
                              hipStream_t stream) {
    const float* day_embed   = (const float*)d_in[0];
    const float* episode_ctx = (const float*)d_in[1];
    const int*   n_episodes  = (const int*)d_in[2];
    const float* W_pool      = (const float*)d_in[3];
    const float* b_pool      = (const float*)d_in[4];
    const float* W1          = (const float*)d_in[5];
    const float* b1          = (const float*)d_in[6];
    const float* W2          = (const float*)d_in[7];
    const float* b2          = (const float*)d_in[8];
    float* out = (float*)d_out;

    float* x_T  = (float*)d_ws;              // [3584][64]
    float* part = x_T + (size_t)DIN * B;     // [16][64][512]

    dim3 gA(NH + 1, B);
    binpool_kernel<<<gA, 256, 0, stream>>>(day_embed, episode_ctx, n_episodes,
                                           W_pool, b_pool, x_T);
    dim3 gB(32, SLABS);
    mlp1_kernel<<<gB, 256, 0, stream>>>(x_T, W1, part);

    tail_kernel<<<64, 256, 0, stream>>>(part, b1, W2, b2, out);
}

// Round 2
// 391.365 us; speedup vs baseline: 1.0849x; 1.0601x over previous
//
#include <hip/hip_runtime.h>
#include <math.h>

#define NH    24
#define DM    512
#define DP    128
#define EMAX  2048
#define DIN   3584   // 512 + 24*128
#define B     64
#define SLABS 32     // K slabs in mlp1
#define SROWS 112    // rows per slab (32*112 = 3584)

// ws layout (floats):
//   x_T   [DIN][B]       = 229376 f
//   part  [SLABS][B][DM] = 1048576 f

// ---------------------------------------------------------------------------
// K1: per-(b,h) bin mean of episode_ctx (contiguous slice), project through
//     W_pool, write x_T[512 + h*128 + k][b]. Block h==24 copies day_embed.
// grid (25, 64), block 256
// Mean phase: float4 loads, thread t = (ep_parity = t>>7, dim-quad p = t&127);
// unroll 4 -> 4 episodes in flight per thread pair (HBM-floor bound).
// Projection: all 4 waves (wave g covers d in [128g,128g+128)), LDS reduce —
// removes the 1-wave serial tail of the previous version.
// ---------------------------------------------------------------------------
__global__ void binpool_kernel(const float* __restrict__ day_embed,
                               const float* __restrict__ episode_ctx,
                               const int* __restrict__ n_episodes,
                               const float* __restrict__ W_pool,
                               const float* __restrict__ b_pool,
                               float* __restrict__ x_T) {
    const int h = blockIdx.x;   // 0..24 (24 == day_embed copy)
    const int b = blockIdx.y;
    const int t = threadIdx.x;  // 0..255

    if (h == NH) {
        for (int i = t; i < DM; i += 256)
            x_T[(size_t)i * B + b] = day_embed[b * DM + i];
        return;
    }

    const int n  = n_episodes[b];
    int bs = n / NH; if (bs < 1) bs = 1;
    const int lo = h * bs;
    int hi = lo + bs; if (hi > n) hi = n;
    int count = hi - lo; if (count < 0) count = 0;

    __shared__ float4 sh4[256];
    __shared__ float  sh_mean[DM];
    __shared__ float  redp[4][DP];

    const int p  = t & 127;     // dim quad: dims 4p..4p+3
    const int eo = t >> 7;      // episode parity

    float4 a = make_float4(0.f, 0.f, 0.f, 0.f);
    const float4* base = (const float4*)episode_ctx
                       + (size_t)b * EMAX * (DM / 4) + p;
    #pragma unroll 4
    for (int e = lo + eo; e < hi; e += 2) {
        float4 v = base[(size_t)e * (DM / 4)];
        a.x += v.x; a.y += v.y; a.z += v.z; a.w += v.w;
    }
    sh4[t] = a;
    __syncthreads();

    if (t < 128) {
        const float inv = (count > 0) ? (1.0f / (float)count) : 0.0f;
        float4 u = sh4[t], v = sh4[t + 128];
        sh_mean[4 * t]     = (u.x + v.x) * inv;
        sh_mean[4 * t + 1] = (u.y + v.y) * inv;
        sh_mean[4 * t + 2] = (u.z + v.z) * inv;
        sh_mean[4 * t + 3] = (u.w + v.w) * inv;
    }
    __syncthreads();

    // projection: wave g = t>>6 handles d in [128g, 128g+128); lane k = t&63
    // computes partial outputs 2k, 2k+1. Then 4-way LDS reduce.
    {
        const int g = t >> 6;
        const int k = t & 63;
        float c0 = 0.f, c1 = 0.f;
        const float2* wp = (const float2*)W_pool + k;
        #pragma unroll 4
        for (int d = g * 128; d < g * 128 + 128; ++d) {
            float m = sh_mean[d];
            float2 w = wp[(size_t)d * (DP / 2)];
            c0 += m * w.x;
            c1 += m * w.y;
        }
        redp[g][2 * k]     = c0;
        redp[g][2 * k + 1] = c1;
    }
    __syncthreads();

    if (t < DP) {
        float v = redp[0][t] + redp[1][t] + redp[2][t] + redp[3][t];
        const int row = DM + h * DP + t;
        x_T[(size_t)row * B + b] = (count > 0) ? (v + b_pool[t]) : 0.f;
    }
}

// ---------------------------------------------------------------------------
// K2: partial GEMM  part[s] = X^T slab . W1 slab
// grid (32, 32): c = 16-col chunk, s = K slab (112 rows). block 256 = 4 waves
// -> 1024 blocks = 4 blocks/CU (16 waves/CU) for latency hiding of cold W1.
// wave w: k in [112s + 28w, +28). lane = batch row (coalesced x_T reads);
// W1 chunk is wave-uniform, float4 loads.
// ---------------------------------------------------------------------------
__global__ void mlp1_kernel(const float* __restrict__ x_T,
                            const float* __restrict__ W1,
                            float* __restrict__ part) {
    const int c = blockIdx.x;
    const int s = blockIdx.y;
    const int t = threadIdx.x;
    const int w = t >> 6;
    const int lane = t & 63;

    float acc[16];
    #pragma unroll
    for (int j = 0; j < 16; ++j) acc[j] = 0.f;

    const int k0 = SROWS * s + 28 * w;
    const float4* wbase = (const float4*)(W1 + (size_t)k0 * DM + 16 * c);
    const float* xbase = x_T + (size_t)k0 * B + lane;

    #pragma unroll 4
    for (int ki = 0; ki < 28; ++ki) {
        float xv = xbase[ki * B];
        const float4* wrow = wbase + (size_t)ki * (DM / 4);
        #pragma unroll
        for (int q = 0; q < 4; ++q) {
            float4 wv = wrow[q];
            acc[4 * q]     += xv * wv.x;
            acc[4 * q + 1] += xv * wv.y;
            acc[4 * q + 2] += xv * wv.z;
            acc[4 * q + 3] += xv * wv.w;
        }
    }

    __shared__ float red[4][64][17];
    #pragma unroll
    for (int j = 0; j < 16; ++j)
        red[w][lane][j] = acc[j];
    __syncthreads();

    for (int idx = t; idx < 1024; idx += 256) {
        const int row = idx >> 4;
        const int j   = idx & 15;
        float v = red[0][row][j] + red[1][row][j] + red[2][row][j] + red[3][row][j];
        part[(size_t)s * (B * DM) + (size_t)row * DM + 16 * c + j] = v;
    }
}

// ---------------------------------------------------------------------------
// K3: per-b: h = gelu(sum_s part[s][b] + b1); out[b] = h @ W2 + b2
// grid 64, block 256
// ---------------------------------------------------------------------------
__global__ void tail_kernel(const float* __restrict__ part,
                            const float* __restrict__ b1,
                            const float* __restrict__ W2,
                            const float* __restrict__ b2,
                            float* __restrict__ out) {
    const int b = blockIdx.x;
    const int t = threadIdx.x;

    __shared__ float sh_h[DM];

    #pragma unroll
    for (int rep = 0; rep < 2; ++rep) {
        const int col = t + rep * 256;
        float v0 = 0.f, v1 = 0.f;
        #pragma unroll
        for (int s = 0; s < SLABS; s += 2) {
            v0 += part[(size_t)s * (B * DM) + (size_t)b * DM + col];
            v1 += part[(size_t)(s + 1) * (B * DM) + (size_t)b * DM + col];
        }
        float v = v0 + v1 + b1[col];
        sh_h[col] = 0.5f * v * (1.0f + erff(v * 0.70710678118654752f));
    }
    __syncthreads();

    if (t < 64) {
        float a0 = 0.f, a1 = 0.f;
        #pragma unroll
        for (int i = t; i < DM; i += 64) {
            float hv = sh_h[i];
            float2 w = ((const float2*)W2)[i];
            a0 += hv * w.x;
            a1 += hv * w.y;
        }
        #pragma unroll
        for (int off = 32; off > 0; off >>= 1) {
            a0 += __shfl_down(a0, off);
            a1 += __shfl_down(a1, off);
        }
        if (t == 0) {
            out[b * 2]     = a0 + b2[0];
            out[b * 2 + 1] = a1 + b2[1];
        }
    }
}

extern "C" void kernel_launch(void* const* d_in, const int* in_sizes, int n_in,
                              void* d_out, int out_size, void* d_ws, size_t ws_size,
                              hipStream_t stream) {
    const float* day_embed   = (const float*)d_in[0];
    const float* episode_ctx = (const float*)d_in[1];
    const int*   n_episodes  = (const int*)d_in[2];
    const float* W_pool      = (const float*)d_in[3];
    const float* b_pool      = (const float*)d_in[4];
    const float* W1          = (const float*)d_in[5];
    const float* b1          = (const float*)d_in[6];
    const float* W2          = (const float*)d_in[7];
    const float* b2          = (const float*)d_in[8];
    float* out = (float*)d_out;

    float* x_T  = (float*)d_ws;              // [3584][64]
    float* part = x_T + (size_t)DIN * B;     // [32][64][512]

    dim3 gA(NH + 1, B);
    binpool_kernel<<<gA, 256, 0, stream>>>(day_embed, episode_ctx, n_episodes,
                                           W_pool, b_pool, x_T);
    dim3 gB(32, SLABS);
    mlp1_kernel<<<gB, 256, 0, stream>>>(x_T, W1, part);

    tail_kernel<<<64, 256, 0, stream>>>(part, b1, W2, b2, out);
}

// Round 3
// 381.071 us; speedup vs baseline: 1.1142x; 1.0270x over previous
//
#include <hip/hip_runtime.h>
#include <math.h>

#define NH    24
#define DM    512
#define DP    128
#define EMAX  2048
#define DIN   3584   // 512 + 24*128
#define B     64
#define SLABS 32     // K slabs in mlp1
#define SROWS 112    // rows per slab (32*112 = 3584)

// ws layout (floats):
//   x_T   [DIN][B]       = 229376 f
//   part  [SLABS][B][DM] = 1048576 f

// ---------------------------------------------------------------------------
// K1: per-(b,h) bin mean of episode_ctx (contiguous slice), project through
//     W_pool, write x_T[512 + h*128 + k][b]. Block h==24 copies day_embed.
// grid (25, 64), block 256
// Mean phase: float4 loads, thread t = (ep_parity = t>>7, dim-quad p = t&127);
// already at the HBM equal-rate-drain floor (~21 us aggregate).
// Projection: 4 waves x (2 d-rows/iter via float4 W_pool, lanes 0-31 = row d
// k-quads, lanes 32-63 = row d+1), unroll 8 -> 8 coalesced 1KB loads in
// flight; cuts the latency-bound tail on critical-path blocks ~2.7->~0.7 us.
// ---------------------------------------------------------------------------
__global__ void binpool_kernel(const float* __restrict__ day_embed,
                               const float* __restrict__ episode_ctx,
                               const int* __restrict__ n_episodes,
                               const float* __restrict__ W_pool,
                               const float* __restrict__ b_pool,
                               float* __restrict__ x_T) {
    const int h = blockIdx.x;   // 0..24 (24 == day_embed copy)
    const int b = blockIdx.y;
    const int t = threadIdx.x;  // 0..255

    if (h == NH) {
        for (int i = t; i < DM; i += 256)
            x_T[(size_t)i * B + b] = day_embed[b * DM + i];
        return;
    }

    const int n  = n_episodes[b];
    int bs = n / NH; if (bs < 1) bs = 1;
    const int lo = h * bs;
    int hi = lo + bs; if (hi > n) hi = n;
    int count = hi - lo; if (count < 0) count = 0;

    __shared__ float4 sh4[256];
    __shared__ float  sh_mean[DM];
    __shared__ float4 redp4[8][32];   // (g,dh) partials, 4 KB

    const int p  = t & 127;     // dim quad: dims 4p..4p+3
    const int eo = t >> 7;      // episode parity

    float4 a = make_float4(0.f, 0.f, 0.f, 0.f);
    const float4* base = (const float4*)episode_ctx
                       + (size_t)b * EMAX * (DM / 4) + p;
    #pragma unroll 4
    for (int e = lo + eo; e < hi; e += 2) {
        float4 v = base[(size_t)e * (DM / 4)];
        a.x += v.x; a.y += v.y; a.z += v.z; a.w += v.w;
    }
    sh4[t] = a;
    __syncthreads();

    if (t < 128) {
        const float inv = (count > 0) ? (1.0f / (float)count) : 0.0f;
        float4 u = sh4[t], v = sh4[t + 128];
        sh_mean[4 * t]     = (u.x + v.x) * inv;
        sh_mean[4 * t + 1] = (u.y + v.y) * inv;
        sh_mean[4 * t + 2] = (u.z + v.z) * inv;
        sh_mean[4 * t + 3] = (u.w + v.w) * inv;
    }
    __syncthreads();

    // projection: wave g owns d in [128g, 128g+128).
    // lane = (dh = lane>>5, kq = lane&31): d-parity dh, k-quad 4kq..4kq+3.
    // Wave iteration reads W_pool rows d, d+1 as one contiguous 1 KB fetch.
    {
        const int g    = t >> 6;
        const int lane = t & 63;
        const int dh   = lane >> 5;
        const int kq   = lane & 31;
        float4 acc = make_float4(0.f, 0.f, 0.f, 0.f);
        const float4* wp4 = (const float4*)W_pool + kq;  // row stride = 32 float4
        const int d0 = g * 128 + dh;
        #pragma unroll 8
        for (int di = 0; di < 64; ++di) {
            const int d = d0 + 2 * di;
            float  m = sh_mean[d];
            float4 w = wp4[(size_t)d * (DP / 4)];
            acc.x += m * w.x; acc.y += m * w.y;
            acc.z += m * w.z; acc.w += m * w.w;
        }
        redp4[2 * g + dh][kq] = acc;
    }
    __syncthreads();

    if (t < DP) {
        const float* rp = (const float*)redp4;
        float v = 0.f;
        #pragma unroll
        for (int r = 0; r < 8; ++r) v += rp[r * DP + t];
        const int row = DM + h * DP + t;
        x_T[(size_t)row * B + b] = (count > 0) ? (v + b_pool[t]) : 0.f;
    }
}

// ---------------------------------------------------------------------------
// K2: partial GEMM  part[s] = X^T slab . W1 slab
// grid (32, 32): c = 16-col chunk, s = K slab (112 rows). block 256 = 4 waves
// -> 1024 blocks = 4 blocks/CU (16 waves/CU) for latency hiding of cold W1.
// wave w: k in [112s + 28w, +28). lane = batch row (coalesced x_T reads);
// W1 chunk is wave-uniform, float4 loads.
// ---------------------------------------------------------------------------
__global__ void mlp1_kernel(const float* __restrict__ x_T,
                            const float* __restrict__ W1,
                            float* __restrict__ part) {
    const int c = blockIdx.x;
    const int s = blockIdx.y;
    const int t = threadIdx.x;
    const int w = t >> 6;
    const int lane = t & 63;

    float acc[16];
    #pragma unroll
    for (int j = 0; j < 16; ++j) acc[j] = 0.f;

    const int k0 = SROWS * s + 28 * w;
    const float4* wbase = (const float4*)(W1 + (size_t)k0 * DM + 16 * c);
    const float* xbase = x_T + (size_t)k0 * B + lane;

    #pragma unroll 4
    for (int ki = 0; ki < 28; ++ki) {
        float xv = xbase[ki * B];
        const float4* wrow = wbase + (size_t)ki * (DM / 4);
        #pragma unroll
        for (int q = 0; q < 4; ++q) {
            float4 wv = wrow[q];
            acc[4 * q]     += xv * wv.x;
            acc[4 * q + 1] += xv * wv.y;
            acc[4 * q + 2] += xv * wv.z;
            acc[4 * q + 3] += xv * wv.w;
        }
    }

    __shared__ float red[4][64][17];
    #pragma unroll
    for (int j = 0; j < 16; ++j)
        red[w][lane][j] = acc[j];
    __syncthreads();

    for (int idx = t; idx < 1024; idx += 256) {
        const int row = idx >> 4;
        const int j   = idx & 15;
        float v = red[0][row][j] + red[1][row][j] + red[2][row][j] + red[3][row][j];
        part[(size_t)s * (B * DM) + (size_t)row * DM + 16 * c + j] = v;
    }
}

// ---------------------------------------------------------------------------
// K3: per-b: h = gelu(sum_s part[s][b] + b1); out[b] = h @ W2 + b2
// grid 64, block 256
// ---------------------------------------------------------------------------
__global__ void tail_kernel(const float* __restrict__ part,
                            const float* __restrict__ b1,
                            const float* __restrict__ W2,
                            const float* __restrict__ b2,
                            float* __restrict__ out) {
    const int b = blockIdx.x;
    const int t = threadIdx.x;

    __shared__ float sh_h[DM];

    #pragma unroll
    for (int rep = 0; rep < 2; ++rep) {
        const int col = t + rep * 256;
        float v0 = 0.f, v1 = 0.f;
        #pragma unroll
        for (int s = 0; s < SLABS; s += 2) {
            v0 += part[(size_t)s * (B * DM) + (size_t)b * DM + col];
            v1 += part[(size_t)(s + 1) * (B * DM) + (size_t)b * DM + col];
        }
        float v = v0 + v1 + b1[col];
        sh_h[col] = 0.5f * v * (1.0f + erff(v * 0.70710678118654752f));
    }
    __syncthreads();

    if (t < 64) {
        float a0 = 0.f, a1 = 0.f;
        #pragma unroll
        for (int i = t; i < DM; i += 64) {
            float hv = sh_h[i];
            float2 w = ((const float2*)W2)[i];
            a0 += hv * w.x;
            a1 += hv * w.y;
        }
        #pragma unroll
        for (int off = 32; off > 0; off >>= 1) {
            a0 += __shfl_down(a0, off);
            a1 += __shfl_down(a1, off);
        }
        if (t == 0) {
            out[b * 2]     = a0 + b2[0];
            out[b * 2 + 1] = a1 + b2[1];
        }
    }
}

extern "C" void kernel_launch(void* const* d_in, const int* in_sizes, int n_in,
                              void* d_out, int out_size, void* d_ws, size_t ws_size,
                              hipStream_t stream) {
    const float* day_embed   = (const float*)d_in[0];
    const float* episode_ctx = (const float*)d_in[1];
    const int*   n_episodes  = (const int*)d_in[2];
    const float* W_pool      = (const float*)d_in[3];
    const float* b_pool      = (const float*)d_in[4];
    const float* W1          = (const float*)d_in[5];
    const float* b1          = (const float*)d_in[6];
    const float* W2          = (const float*)d_in[7];
    const float* b2          = (const float*)d_in[8];
    float* out = (float*)d_out;

    float* x_T  = (float*)d_ws;              // [3584][64]
    float* part = x_T + (size_t)DIN * B;     // [32][64][512]

    dim3 gA(NH + 1, B);
    binpool_kernel<<<gA, 256, 0, stream>>>(day_embed, episode_ctx, n_episodes,
                                           W_pool, b_pool, x_T);
    dim3 gB(32, SLABS);
    mlp1_kernel<<<gB, 256, 0, stream>>>(x_T, W1, part);

    tail_kernel<<<64, 256, 0, stream>>>(part, b1, W2, b2, out);
}